// Round 7
// baseline (4938.421 us; speedup 1.0000x reference)
//
#include <hip/hip_runtime.h>
#include <cstdint>
#include <cstddef>

// Problem constants
#define HN 304      // hidden size
#define G3 912      // 3*HN gate rows
#define UW 38       // hidden units per slice (HN/8)  -- R7: 8 slices
#define KQ 76       // k-quarter span (HN/4)
#define NB 64       // batch
#define TSTEPS 1024 // encoder steps
#define LDEC 127    // decoder steps actually needed (L-1)
#define DCLS 128    // vocab / classes

// Output layout (floats): [softmax_cal 8128*128][target_cal 8128][asr_outputs 8128]
#define OUT_O1 1040384
#define OUT_O2 1048512

// Workspace layout (bytes). Proven available: ws_size >= 239,702,784.
static const size_t OFF_GI   = 0;             // 64*1024*912 f32 = 239,075,328
static const size_t OFF_HP   = 239075328ull;  // tagged h ping-pong: 2*64*304 u32
static const size_t OFF_AM   = 239230976ull;  // (spare)
static const size_t OFF_ABRT = 239233024ull;  // 256
static const size_t OFF_TAB  = 239233280ull;  // 128*912 f32
static const size_t WS_NEED  = 239700224ull;

// Dynamic-LDS layout for rnn_persist (float offsets).
//  linw_s: 128x304 at stride 306 (decoder linear layer)
//  hbq: h for the 2 batches [2][304] (tagged values, like proven kernel)
//  partU: encoder GEMV partials [2][4][114] (912) / decoder logits [256]
#define SM_LINW   0        // 39168 floats
#define SM_HB     39168    // 608 floats (2*304, 16B-aligned)
#define SM_U      39776    // 912 floats
#define SM_AMXV   40688    // 8 floats
#define SM_AMXI   40696    // 8 ints
#define SM_FLOATS 40704
#define SMEM_BYTES (SM_FLOATS * 4)   // 162,816 <= 163,840 (160 KiB)

// Packed f32 FMA (VOP3P) — gi_gemm only; bit-identical to scalar chain.
#define PKFMA_L(C2, A2, B2) \
    asm("v_pk_fma_f32 %0, %1, %2, %0 op_sel:[0,0,0] op_sel_hi:[0,1,1]" \
        : "+v"(C2) : "v"(A2), "v"(B2))
#define PKFMA_H(C2, A2, B2) \
    asm("v_pk_fma_f32 %0, %1, %2, %0 op_sel:[1,0,0] op_sel_hi:[1,1,1]" \
        : "+v"(C2) : "v"(A2), "v"(B2))

// Opaque keep-alive (blocks rematerialization of weight loads).
#define KEEP4(V) asm volatile("" : "+v"((V).x), "+v"((V).y), "+v"((V).z), "+v"((V).w))

#define REP19(M) M(0) M(1) M(2) M(3) M(4) M(5) M(6) M(7) M(8) M(9) M(10) M(11) M(12) M(13) M(14) M(15) M(16) M(17) M(18)

// ---------------------------------------------------------------------------
// Phase 1: gi GEMM (unchanged, proven R4 pk-fma version)
// ---------------------------------------------------------------------------
__global__ __launch_bounds__(256) void gi_gemm(const float* __restrict__ X,
                                               const float* __restrict__ W,
                                               const float* __restrict__ bias,
                                               float* __restrict__ out)
{
    __shared__ float As[16][132];
    __shared__ float Bs[16][132];
    const int tid = threadIdx.x;
    const int m0 = blockIdx.x * 128;
    const int n0 = blockIdx.y * 128;
    const int tx = tid & 15;
    const int ty = tid >> 4;
    const int lr = tid >> 1;
    const int lc = (tid & 1) * 8;

    float2 c2[8][4];
#pragma unroll
    for (int i = 0; i < 8; ++i)
#pragma unroll
        for (int j = 0; j < 4; ++j) { c2[i][j].x = 0.f; c2[i][j].y = 0.f; }

    const bool wok = (n0 + lr < G3);
    const float* xrow = X + (size_t)(m0 + lr) * HN;
    const float* wrow = W + (size_t)(n0 + lr) * HN;
    const float4 z4 = make_float4(0.f, 0.f, 0.f, 0.f);

    float4 xa = *(const float4*)(xrow + lc);
    float4 xb = *(const float4*)(xrow + lc + 4);
    float4 wa = wok ? *(const float4*)(wrow + lc) : z4;
    float4 wb = wok ? *(const float4*)(wrow + lc + 4) : z4;

    for (int k0 = 0; k0 < HN; k0 += 16) {
        As[lc + 0][lr] = xa.x; As[lc + 1][lr] = xa.y; As[lc + 2][lr] = xa.z; As[lc + 3][lr] = xa.w;
        As[lc + 4][lr] = xb.x; As[lc + 5][lr] = xb.y; As[lc + 6][lr] = xb.z; As[lc + 7][lr] = xb.w;
        Bs[lc + 0][lr] = wa.x; Bs[lc + 1][lr] = wa.y; Bs[lc + 2][lr] = wa.z; Bs[lc + 3][lr] = wa.w;
        Bs[lc + 4][lr] = wb.x; Bs[lc + 5][lr] = wb.y; Bs[lc + 6][lr] = wb.z; Bs[lc + 7][lr] = wb.w;
        __syncthreads();
        if (k0 + 16 < HN) {
            xa = *(const float4*)(xrow + k0 + 16 + lc);
            xb = *(const float4*)(xrow + k0 + 16 + lc + 4);
            if (wok) {
                wa = *(const float4*)(wrow + k0 + 16 + lc);
                wb = *(const float4*)(wrow + k0 + 16 + lc + 4);
            }
        }
#pragma unroll
        for (int kk = 0; kk < 16; ++kk) {
            const float2* ar = (const float2*)&As[kk][ty * 8];
            const float2* br = (const float2*)&Bs[kk][tx * 8];
            float2 ap[4], bp[4];
#pragma unroll
            for (int j = 0; j < 4; ++j) { ap[j] = ar[j]; bp[j] = br[j]; }
#pragma unroll
            for (int p = 0; p < 4; ++p) {
#pragma unroll
                for (int j = 0; j < 4; ++j) {
                    PKFMA_L(c2[2 * p][j],     ap[p], bp[j]);
                    PKFMA_H(c2[2 * p + 1][j], ap[p], bp[j]);
                }
            }
        }
        __syncthreads();
    }

    const int nb = n0 + tx * 8;
    float4 bb0 = (nb + 3 < G3) ? *(const float4*)(bias + nb) : z4;
    float4 bb1 = (nb + 7 < G3) ? *(const float4*)(bias + nb + 4) : z4;
#pragma unroll
    for (int i = 0; i < 8; ++i) {
        const size_t m = (size_t)(m0 + ty * 8 + i);
        if (nb + 3 < G3) {
            float4 v = make_float4(c2[i][0].x + bb0.x, c2[i][0].y + bb0.y,
                                   c2[i][1].x + bb0.z, c2[i][1].y + bb0.w);
            *(float4*)(out + m * G3 + nb) = v;
        }
        if (nb + 7 < G3) {
            float4 v = make_float4(c2[i][2].x + bb1.x, c2[i][2].y + bb1.y,
                                   c2[i][3].x + bb1.z, c2[i][3].y + bb1.w);
            *(float4*)(out + m * G3 + nb + 4) = v;
        }
    }
}

// ---------------------------------------------------------------------------
// Phase 1b: decoder input-projection table (unchanged)
// ---------------------------------------------------------------------------
__global__ __launch_bounds__(256) void table_k(const float* __restrict__ emb,
                                               const float* __restrict__ Wih,
                                               const float* __restrict__ bih,
                                               float* __restrict__ tab)
{
    const int idx = blockIdx.x * 256 + threadIdx.x;
    const int d = idx / G3;
    const int R = idx - d * G3;
    const float4* e4 = (const float4*)(emb + (size_t)d * HN);
    const float4* w4 = (const float4*)(Wih + (size_t)R * HN);
    float acc = 0.f;
#pragma unroll
    for (int j = 0; j < 76; ++j) {
        const float4 e = e4[j], w = w4[j];
        acc += e.x * w.x; acc += e.y * w.y; acc += e.z * w.z; acc += e.w * w.w;
    }
    tab[idx] = acc + bih[R];
}

// target_cal output (unchanged)
__global__ void tcal_k(const int* __restrict__ target, float* __restrict__ out)
{
    const int i = blockIdx.x * 256 + threadIdx.x;
    if (i < NB * LDEC) {
        const int b = i / LDEC;
        const int t = i - b * LDEC;
        out[OUT_O1 + i] = (float)target[b * 128 + t + 1];
    }
}

// ---------------------------------------------------------------------------
// Sync helpers (agent-scope LLC exchange — proven protocol, verbatim).
// ---------------------------------------------------------------------------
__device__ __forceinline__ void barl()
{
    asm volatile("s_waitcnt lgkmcnt(0)\n\ts_barrier" ::: "memory");
}

__device__ __forceinline__ void pub32(unsigned int* p, unsigned v)
{
    __hip_atomic_store(p, v, __ATOMIC_RELAXED, __HIP_MEMORY_SCOPE_AGENT);
}

__device__ __forceinline__ unsigned poll_tag32(unsigned int* p, unsigned want, int* abortf)
{
    unsigned v; int g = 0;
    for (;;) {
        v = __hip_atomic_load(p, __ATOMIC_RELAXED, __HIP_MEMORY_SCOPE_AGENT);
        if ((v & 3u) == want) break;
        if ((++g & 255) == 0) {
            if (__hip_atomic_load(abortf, __ATOMIC_RELAXED, __HIP_MEMORY_SCOPE_AGENT) != 0) break;
            if (g > (1 << 19)) {
                __hip_atomic_store(abortf, 1, __ATOMIC_RELAXED, __HIP_MEMORY_SCOPE_AGENT);
                break;
            }
        }
    }
    __asm__ volatile("" ::: "memory");
    return v;
}

// Dual poll: both loads stay in flight concurrently -> ~1 LLC latency for 2 slots.
__device__ __forceinline__ void poll2(unsigned int* pa, unsigned int* pb, unsigned want,
                                      int* abortf, unsigned& va, unsigned& vb)
{
    int g = 0; bool da = false, db = false;
    for (;;) {
        if (!da) { unsigned v = __hip_atomic_load(pa, __ATOMIC_RELAXED, __HIP_MEMORY_SCOPE_AGENT);
                   if ((v & 3u) == want) { va = v; da = true; } }
        if (!db) { unsigned v = __hip_atomic_load(pb, __ATOMIC_RELAXED, __HIP_MEMORY_SCOPE_AGENT);
                   if ((v & 3u) == want) { vb = v; db = true; } }
        if (da && db) break;
        if ((++g & 255) == 0) {
            if (__hip_atomic_load(abortf, __ATOMIC_RELAXED, __HIP_MEMORY_SCOPE_AGENT) != 0) break;
            if (g > (1 << 19)) {
                __hip_atomic_store(abortf, 1, __ATOMIC_RELAXED, __HIP_MEMORY_SCOPE_AGENT);
                break;
            }
        }
    }
    __asm__ volatile("" ::: "memory");
}

// Weight registers: 19 named float4 (one GEMV row, one k-quarter).
#define DECLW(j) float4 w##j;
#define LDWJ(j)  w##j = wp_[j]; KEEP4(w##j);
#define LOAD_WEIGHTS(SRC) do { if (comp) { \
    const float4* wp_ = (const float4*)((SRC) + (size_t)Rrow * HN + (size_t)ksq * KQ); \
    REP19(LDWJ) } } while (0)

// GEMV MAC for one float4 of weights, both batches (each accumulator's chain
// is ascending-k scalar FMAs -> per-(row,batch) bit-identical to proven kernel).
#define MACJ(j) { const float4 h0v = hp0[j], h1v = hp1[j]; \
    a0 += w##j.x * h0v.x; a0 += w##j.y * h0v.y; a0 += w##j.z * h0v.z; a0 += w##j.w * h0v.w; \
    a1 += w##j.x * h1v.x; a1 += w##j.y * h1v.y; a1 += w##j.z * h1v.z; a1 += w##j.w * h1v.w; }

// One GRU step for both batches.  Arithmetic per (unit,batch) is verbatim from
// the proven kernel: 4 ascending k-quarter partials + bias, same nonlinearity,
// same tag-stomped h, same parity/tag exchange protocol.
#define RNN_STEP(T_, GR, GZ, GN) do {                                               \
    if (comp) {                                                                     \
        const float4* hp0 = (const float4*)(hbq + ksq * KQ);                        \
        const float4* hp1 = (const float4*)(hbq + 304 + ksq * KQ);                  \
        float a0 = 0.f, a1 = 0.f;                                                   \
        REP19(MACJ)                                                                 \
        partU[ksq * 114 + rr] = a0;                                                 \
        partU[456 + ksq * 114 + rr] = a1;                                           \
    }                                                                               \
    barl();                                                                         \
    if (tid < 76) {                                                                 \
        const int pb_ = fq * 456;                                                   \
        const float ghr = partU[pb_ + fu] + partU[pb_ + 114 + fu]                   \
                        + partU[pb_ + 228 + fu] + partU[pb_ + 342 + fu] + b_r;      \
        const float ghz = partU[pb_ + UW + fu] + partU[pb_ + 114 + UW + fu]         \
                        + partU[pb_ + 228 + UW + fu] + partU[pb_ + 342 + UW + fu] + b_z; \
        const float ghn = partU[pb_ + 2 * UW + fu] + partU[pb_ + 114 + 2 * UW + fu] \
                        + partU[pb_ + 228 + 2 * UW + fu] + partU[pb_ + 342 + 2 * UW + fu] + b_n; \
        const float r_ = 1.f / (1.f + expf(-((GR) + ghr)));                         \
        const float z_ = 1.f / (1.f + expf(-((GZ) + ghz)));                         \
        const float n_ = tanhf((GN) + r_ * ghn);                                    \
        const float hnew = (1.f - z_) * n_ + z_ * hbq[fq * 304 + un];               \
        const unsigned hb_ = (__float_as_uint(hnew) & ~3u) | ((unsigned)(T_) & 3u); \
        hbq[fq * 304 + un] = __uint_as_float(hb_);                                  \
        pub32(hpk + (size_t)(b0 + fq) * HN + ((T_) & 1) * (NB * HN) + un, hb_);     \
    }                                                                               \
    {                                                                               \
        const int pq_ = (tid >= 304) ? 1 : 0;                                       \
        const int pu_ = tid - 304 * pq_;                                            \
        const bool needA = (pu_ / UW != s);                                         \
        const int su_ = 208 + tid;                                                  \
        const bool needB = (tid < 96) && (su_ / UW != s);                           \
        unsigned va_, vb_;                                                          \
        if (needA && needB) {                                                       \
            poll2(hpk + (size_t)(b0 + pq_) * HN + ((T_) & 1) * (NB * HN) + pu_,     \
                  hpk + (size_t)b1 * HN + ((T_) & 1) * (NB * HN) + su_,             \
                  (unsigned)(T_) & 3u, abortf, va_, vb_);                           \
            hbq[pq_ * 304 + pu_] = __uint_as_float(va_);                            \
            hbq[304 + su_] = __uint_as_float(vb_);                                  \
        } else if (needA) {                                                         \
            va_ = poll_tag32(hpk + (size_t)(b0 + pq_) * HN + ((T_) & 1) * (NB * HN) + pu_, \
                             (unsigned)(T_) & 3u, abortf);                          \
            hbq[pq_ * 304 + pu_] = __uint_as_float(va_);                            \
        } else if (needB) {                                                         \
            vb_ = poll_tag32(hpk + (size_t)b1 * HN + ((T_) & 1) * (NB * HN) + su_,  \
                             (unsigned)(T_) & 3u, abortf);                          \
            hbq[304 + su_] = __uint_as_float(vb_);                                  \
        }                                                                           \
    }                                                                               \
    barl();                                                                         \
} while (0)

// ---------------------------------------------------------------------------
// Phase 2: persistent recurrence. 256 WGs x 512 threads, 1 WG/CU (LDS-forced).
// R7: 32 batch-pairs x 8 slices. Per-WG weights 139 KB (was 277), per-thread
// 76 floats (was 152), each used for BOTH batches -> L2 weight stream halves
// worst-case, vanishes if register-resident. Exchange protocol unchanged.
// ---------------------------------------------------------------------------
__global__ __attribute__((amdgpu_waves_per_eu(2, 2)))
__launch_bounds__(512) void rnn_persist(
    const float* __restrict__ gi,
    const float* __restrict__ encWhh, const float* __restrict__ encBhh,
    const float* __restrict__ decWhh, const float* __restrict__ decBhh,
    const float* __restrict__ tab,
    const float* __restrict__ linW, const float* __restrict__ linB,
    const int* __restrict__ target,
    unsigned int* hpk, int* abortf, float* out)
{
    const int w = blockIdx.x;
    const int p = w & 31;          // batch pair 0..31
    const int s = w >> 5;          // slice 0..7
    const int b0 = 2 * p, b1 = 2 * p + 1;
    const int tid = threadIdx.x;

    extern __shared__ float smem[];
    float* linw_s = smem + SM_LINW;
    float* hbq    = smem + SM_HB;      // [2][304] tagged h
    float* partU  = smem + SM_U;       // enc partials / dec logits
    float* amx_vs = smem + SM_AMXV;    // [8]
    int*   amx_is = (int*)(smem + SM_AMXI);

    const bool comp = (tid < 456);
    const int ksq = tid / 114;          // k-quarter 0..3 (comp)
    const int rr  = tid - ksq * 114;    // row-in-slice 0..113
    const int gg  = rr / UW;            // gate 0..2
    const int ulr = rr - gg * UW;       // unit-in-slice of this row
    const int Rrow = gg * HN + s * UW + ulr;  // global gate row

    const int fq = (tid < 76) ? (tid / UW) : 0;  // finisher batch q
    const int fu = tid - (tid / UW) * UW;        // unit-in-slice (tid<76)
    const int un = s * UW + ((tid < 76) ? fu : 0); // global unit (tid<76)

    // ---- stage linW (128x304 -> stride 306) + zero h0 (both batches)
    for (int i = tid; i < DCLS * HN; i += 512) {
        const int r0 = i / HN;
        linw_s[r0 * 306 + (i - r0 * HN)] = linW[i];
    }
    for (int i = tid; i < 608; i += 512) hbq[i] = 0.f;

    // ---- encoder weights: 19 named float4 per comp thread (76 VGPRs)
    REP19(DECLW)
    LOAD_WEIGHTS(encWhh);
    float b_r = 0.f, b_z = 0.f, b_n = 0.f;
    if (tid < 76) { b_r = encBhh[un]; b_z = encBhh[HN + un]; b_n = encBhh[2 * HN + un]; }

    __syncthreads();

    const float* gib = gi + (size_t)(b0 + fq) * TSTEPS * G3;  // valid use: tid<76

    // ================= encoder: 1024 steps, unrolled x2 with gi prefetch =====
    float gAr = 0.f, gAz = 0.f, gAn = 0.f, gBr = 0.f, gBz = 0.f, gBn = 0.f;
    if (tid < 76) { gAr = gib[un]; gAz = gib[HN + un]; gAn = gib[2 * HN + un]; }

    for (int t = 0; t < TSTEPS; t += 2) {
        if (tid < 76) {
            const float* gp = gib + (size_t)(t + 1) * G3;
            gBr = gp[un]; gBz = gp[HN + un]; gBn = gp[2 * HN + un];
        }
        RNN_STEP(t + 1, gAr, gAz, gAn);
        if (tid < 76 && t + 2 < TSTEPS) {
            const float* gp = gib + (size_t)(t + 2) * G3;
            gAr = gp[un]; gAz = gp[HN + un]; gAn = gp[2 * HN + un];
        }
        RNN_STEP(t + 2, gBr, gBz, gBn);
    }

    // ---- decoder weights + biases
    LOAD_WEIGHTS(decWhh);
    if (tid < 76) { b_r = decBhh[un]; b_z = decBhh[HN + un]; b_n = decBhh[2 * HN + un]; }
    int tok0 = target[b0 * 128];
    int tok1 = target[b1 * 128];
    const int rp   = tid >> 1;       // (row,batch) pair id 0..255
    const int lrow = rp & 127;       // logit row
    const int lq   = rp >> 7;        // batch q
    const int kh   = tid & 1;        // k-half 0/1 (slices 4kh..4kh+3)
    const float linb_r = linB[lrow];
    barl();

    // ================= decoder: 127 steps =================
    // All 8 slice-WGs of a pair hold bit-identical hbq after the exchange, so
    // each computes all 2x128 logits locally (8 ascending 38-slices + bias,
    // first-max argmax) -> no cross-WG argmax traffic, consistent tok.
    for (int t = 0; t < LDEC; ++t) {
        const int T = TSTEPS + 1 + t;
        float gr = 0.f, gz = 0.f, gn = 0.f;
        if (tid < 76) {
            const float* tp = tab + (size_t)(fq ? tok1 : tok0) * G3;
            gr = tp[un]; gz = tp[HN + un]; gn = tp[2 * HN + un];
        }
        RNN_STEP(T, gr, gz, gn);

        // logits: thread (row, q, kh) computes 4 slice-partials (38 elems each,
        // 19 float2 ascending) for slices 4kh..4kh+3; odd lane's partials are
        // fetched via shfl_xor(1); even lane sums all 8 ascending + bias.
        {
            const float* wl = linw_s + lrow * 306 + kh * 152;
            const float* hl = hbq + lq * 304 + kh * 152;
            float p0 = 0.f, p1 = 0.f, p2 = 0.f, p3 = 0.f;
#pragma unroll
            for (int j = 0; j < 19; ++j) {
                const float2 wv = *(const float2*)(wl + 2 * j);
                const float2 hv = *(const float2*)(hl + 2 * j);
                p0 += wv.x * hv.x; p0 += wv.y * hv.y;
            }
#pragma unroll
            for (int j = 0; j < 19; ++j) {
                const float2 wv = *(const float2*)(wl + 38 + 2 * j);
                const float2 hv = *(const float2*)(hl + 38 + 2 * j);
                p1 += wv.x * hv.x; p1 += wv.y * hv.y;
            }
#pragma unroll
            for (int j = 0; j < 19; ++j) {
                const float2 wv = *(const float2*)(wl + 76 + 2 * j);
                const float2 hv = *(const float2*)(hl + 76 + 2 * j);
                p2 += wv.x * hv.x; p2 += wv.y * hv.y;
            }
#pragma unroll
            for (int j = 0; j < 19; ++j) {
                const float2 wv = *(const float2*)(wl + 114 + 2 * j);
                const float2 hv = *(const float2*)(hl + 114 + 2 * j);
                p3 += wv.x * hv.x; p3 += wv.y * hv.y;
            }
            const float q0 = __shfl_xor(p0, 1);
            const float q1 = __shfl_xor(p1, 1);
            const float q2 = __shfl_xor(p2, 1);
            const float q3 = __shfl_xor(p3, 1);
            if (!(tid & 1)) {
                float lg = p0; lg += p1; lg += p2; lg += p3;
                lg += q0; lg += q1; lg += q2; lg += q3; lg += linb_r;
                partU[rp] = lg;
                if ((lrow >> 4) == s)
                    out[((size_t)(b0 + lq) * LDEC + t) * DCLS + lrow] = lg;
            }
        }
        barl();
        if (tid < 8) {                 // per-batch group argmax (first-max wins)
            const int q_ = tid >> 2, grp = tid & 3;
            const float* lp_ = partU + q_ * 128 + grp * 32;
            float bv = lp_[0]; int bi = 0;
            for (int i = 1; i < 32; ++i) {
                const float v = lp_[i];
                if (v > bv) { bv = v; bi = i; }
            }
            amx_vs[tid] = bv; amx_is[tid] = grp * 32 + bi;
        }
        barl();
        {                              // identical winners on all threads, all WGs
            float gbv = amx_vs[0]; int gbi = amx_is[0];
            if (amx_vs[1] > gbv) { gbv = amx_vs[1]; gbi = amx_is[1]; }
            if (amx_vs[2] > gbv) { gbv = amx_vs[2]; gbi = amx_is[2]; }
            if (amx_vs[3] > gbv) { gbv = amx_vs[3]; gbi = amx_is[3]; }
            tok0 = gbi;
            float gbv1 = amx_vs[4]; int gbi1 = amx_is[4];
            if (amx_vs[5] > gbv1) { gbv1 = amx_vs[5]; gbi1 = amx_is[5]; }
            if (amx_vs[6] > gbv1) { gbv1 = amx_vs[6]; gbi1 = amx_is[6]; }
            if (amx_vs[7] > gbv1) { gbv1 = amx_vs[7]; gbi1 = amx_is[7]; }
            tok1 = gbi1;
            if (tid == 0 && s == 0) {
                out[OUT_O2 + (size_t)b0 * LDEC + t] = (float)tok0;
                out[OUT_O2 + (size_t)b1 * LDEC + t] = (float)tok1;
            }
        }
    }
}

// ---------------------------------------------------------------------------
extern "C" void kernel_launch(void* const* d_in, const int* in_sizes, int n_in,
                              void* d_out, int out_size, void* d_ws, size_t ws_size,
                              hipStream_t stream)
{
    (void)in_sizes; (void)n_in; (void)out_size;
    const float* x      = (const float*)d_in[0];
    const int*   target = (const int*)  d_in[1];
    const float* emb    = (const float*)d_in[2];
    const float* encWih = (const float*)d_in[3];
    const float* encWhh = (const float*)d_in[4];
    const float* encBih = (const float*)d_in[5];
    const float* encBhh = (const float*)d_in[6];
    const float* decWih = (const float*)d_in[7];
    const float* decWhh = (const float*)d_in[8];
    const float* decBih = (const float*)d_in[9];
    const float* decBhh = (const float*)d_in[10];
    const float* linW   = (const float*)d_in[11];
    const float* linB   = (const float*)d_in[12];
    float* out = (float*)d_out;
    char* ws = (char*)d_ws;

    if (ws_size < WS_NEED) return;  // insufficient scratch: fail visibly

    float*        gi   = (float*)(ws + OFF_GI);
    unsigned int* hpk  = (unsigned int*)(ws + OFF_HP);
    int*          abrt = (int*)(ws + OFF_ABRT);
    float*        tab  = (float*)(ws + OFF_TAB);

    // opt-in to >64KB dynamic LDS for rnn_persist (one-time, capture-safe)
    static bool s_attr_done = false;
    if (!s_attr_done) {
        (void)hipFuncSetAttribute(reinterpret_cast<const void*>(rnn_persist),
                                  hipFuncAttributeMaxDynamicSharedMemorySize, SMEM_BYTES);
        s_attr_done = true;
    }

    // zero tagged-h ping-pong + abort flag
    (void)hipMemsetAsync(ws + OFF_HP, 0, OFF_TAB - OFF_HP, stream);
    gi_gemm<<<dim3(512, 8), 256, 0, stream>>>(x, encWih, encBih, gi);
    table_k<<<456, 256, 0, stream>>>(emb, decWih, decBih, tab);
    tcal_k<<<32, 256, 0, stream>>>(target, out);
    rnn_persist<<<256, 512, SMEM_BYTES, stream>>>(gi, encWhh, encBhh, decWhh, decBhh, tab,
                                                  linW, linB, target, hpk, abrt, out);
}

// Round 8
// 3339.098 us; speedup vs baseline: 1.4790x; 1.4790x over previous
//
#include <hip/hip_runtime.h>
#include <cstdint>
#include <cstddef>

// Problem constants
#define HN 304      // hidden size
#define G3 912      // 3*HN gate rows
#define US 76       // hidden units per slice (HN/4)
#define RS 228      // rows per slice (3*US)
#define NB 64       // batch
#define TSTEPS 1024 // encoder steps
#define LDEC 127    // decoder steps actually needed (L-1)
#define DCLS 128    // vocab / classes

// Output layout (floats): [softmax_cal 8128*128][target_cal 8128][asr_outputs 8128]
#define OUT_O1 1040384
#define OUT_O2 1048512

// Workspace layout (bytes). Proven available: ws_size >= 239,702,784.
static const size_t OFF_GI   = 0;             // 64*1024*912 f32 = 239,075,328
static const size_t OFF_HP   = 239075328ull;  // tagged h ping-pong: 2*64*304 u32
static const size_t OFF_AM   = 239230976ull;  // argmax tagged: 64*4 ull
static const size_t OFF_ABRT = 239233024ull;  // 256
static const size_t OFF_TAB  = 239233280ull;  // 128*912 f32
static const size_t WS_NEED  = 239700224ull;

// Dynamic-LDS layout for rnn_persist (float offsets).
//  w2t: second row-set weights, transposed conflict-free layout:
//       float4 index (ksq*19 + j)*114 + lp, elems contiguous. 34656 floats.
#define SM_W2T    0        // 34656 floats (138,624 B)
#define SM_HB     34656    // 304 floats (16B aligned)
#define SM_PART   34960    // 912 floats  [4][228]
#define SM_LPART  35872    // 288 floats  [32][9]
#define SM_LOGS   36160    // 32 floats
#define SM_AMXV   36192    // 4 floats
#define SM_AMXI   36196    // 4 ints
#define SM_FLOATS 36200
#define SMEM_BYTES (SM_FLOATS * 4)   // 144,800 <= 163,840 (160 KiB)

// Packed f32 FMA (VOP3P) — gi_gemm only; bit-identical to scalar chain.
#define PKFMA_L(C2, A2, B2) \
    asm("v_pk_fma_f32 %0, %1, %2, %0 op_sel:[0,0,0] op_sel_hi:[0,1,1]" \
        : "+v"(C2) : "v"(A2), "v"(B2))
#define PKFMA_H(C2, A2, B2) \
    asm("v_pk_fma_f32 %0, %1, %2, %0 op_sel:[1,0,0] op_sel_hi:[1,1,1]" \
        : "+v"(C2) : "v"(A2), "v"(B2))

// ---------------------------------------------------------------------------
// Phase 1: gi GEMM (proven R4 pk-fma version, unchanged)
// ---------------------------------------------------------------------------
__global__ __launch_bounds__(256) void gi_gemm(const float* __restrict__ X,
                                               const float* __restrict__ W,
                                               const float* __restrict__ bias,
                                               float* __restrict__ out)
{
    __shared__ float As[16][132];
    __shared__ float Bs[16][132];
    const int tid = threadIdx.x;
    const int m0 = blockIdx.x * 128;
    const int n0 = blockIdx.y * 128;
    const int tx = tid & 15;
    const int ty = tid >> 4;
    const int lr = tid >> 1;
    const int lc = (tid & 1) * 8;

    float2 c2[8][4];
#pragma unroll
    for (int i = 0; i < 8; ++i)
#pragma unroll
        for (int j = 0; j < 4; ++j) { c2[i][j].x = 0.f; c2[i][j].y = 0.f; }

    const bool wok = (n0 + lr < G3);
    const float* xrow = X + (size_t)(m0 + lr) * HN;
    const float* wrow = W + (size_t)(n0 + lr) * HN;
    const float4 z4 = make_float4(0.f, 0.f, 0.f, 0.f);

    float4 xa = *(const float4*)(xrow + lc);
    float4 xb = *(const float4*)(xrow + lc + 4);
    float4 wa = wok ? *(const float4*)(wrow + lc) : z4;
    float4 wb = wok ? *(const float4*)(wrow + lc + 4) : z4;

    for (int k0 = 0; k0 < HN; k0 += 16) {
        As[lc + 0][lr] = xa.x; As[lc + 1][lr] = xa.y; As[lc + 2][lr] = xa.z; As[lc + 3][lr] = xa.w;
        As[lc + 4][lr] = xb.x; As[lc + 5][lr] = xb.y; As[lc + 6][lr] = xb.z; As[lc + 7][lr] = xb.w;
        Bs[lc + 0][lr] = wa.x; Bs[lc + 1][lr] = wa.y; Bs[lc + 2][lr] = wa.z; Bs[lc + 3][lr] = wa.w;
        Bs[lc + 4][lr] = wb.x; Bs[lc + 5][lr] = wb.y; Bs[lc + 6][lr] = wb.z; Bs[lc + 7][lr] = wb.w;
        __syncthreads();
        if (k0 + 16 < HN) {
            xa = *(const float4*)(xrow + k0 + 16 + lc);
            xb = *(const float4*)(xrow + k0 + 16 + lc + 4);
            if (wok) {
                wa = *(const float4*)(wrow + k0 + 16 + lc);
                wb = *(const float4*)(wrow + k0 + 16 + lc + 4);
            }
        }
#pragma unroll
        for (int kk = 0; kk < 16; ++kk) {
            const float2* ar = (const float2*)&As[kk][ty * 8];
            const float2* br = (const float2*)&Bs[kk][tx * 8];
            float2 ap[4], bp[4];
#pragma unroll
            for (int j = 0; j < 4; ++j) { ap[j] = ar[j]; bp[j] = br[j]; }
#pragma unroll
            for (int p = 0; p < 4; ++p) {
#pragma unroll
                for (int j = 0; j < 4; ++j) {
                    PKFMA_L(c2[2 * p][j],     ap[p], bp[j]);
                    PKFMA_H(c2[2 * p + 1][j], ap[p], bp[j]);
                }
            }
        }
        __syncthreads();
    }

    const int nb = n0 + tx * 8;
    float4 bb0 = (nb + 3 < G3) ? *(const float4*)(bias + nb) : z4;
    float4 bb1 = (nb + 7 < G3) ? *(const float4*)(bias + nb + 4) : z4;
#pragma unroll
    for (int i = 0; i < 8; ++i) {
        const size_t m = (size_t)(m0 + ty * 8 + i);
        if (nb + 3 < G3) {
            float4 v = make_float4(c2[i][0].x + bb0.x, c2[i][0].y + bb0.y,
                                   c2[i][1].x + bb0.z, c2[i][1].y + bb0.w);
            *(float4*)(out + m * G3 + nb) = v;
        }
        if (nb + 7 < G3) {
            float4 v = make_float4(c2[i][2].x + bb1.x, c2[i][2].y + bb1.y,
                                   c2[i][3].x + bb1.z, c2[i][3].y + bb1.w);
            *(float4*)(out + m * G3 + nb + 4) = v;
        }
    }
}

// ---------------------------------------------------------------------------
// Phase 1b: decoder input-projection table (unchanged)
// ---------------------------------------------------------------------------
__global__ __launch_bounds__(256) void table_k(const float* __restrict__ emb,
                                               const float* __restrict__ Wih,
                                               const float* __restrict__ bih,
                                               float* __restrict__ tab)
{
    const int idx = blockIdx.x * 256 + threadIdx.x;
    const int d = idx / G3;
    const int R = idx - d * G3;
    const float4* e4 = (const float4*)(emb + (size_t)d * HN);
    const float4* w4 = (const float4*)(Wih + (size_t)R * HN);
    float acc = 0.f;
#pragma unroll
    for (int j = 0; j < 76; ++j) {
        const float4 e = e4[j], w = w4[j];
        acc += e.x * w.x; acc += e.y * w.y; acc += e.z * w.z; acc += e.w * w.w;
    }
    tab[idx] = acc + bih[R];
}

// target_cal output (unchanged)
__global__ void tcal_k(const int* __restrict__ target, float* __restrict__ out)
{
    const int i = blockIdx.x * 256 + threadIdx.x;
    if (i < NB * LDEC) {
        const int b = i / LDEC;
        const int t = i - b * LDEC;
        out[OUT_O1 + i] = (float)target[b * 128 + t + 1];
    }
}

// ---------------------------------------------------------------------------
// Self-tagged poll (proven R0 form).
// ---------------------------------------------------------------------------
__device__ __forceinline__ unsigned poll_tag32(unsigned int* p, unsigned want, int* abortf)
{
    unsigned v; int g = 0;
    for (;;) {
        v = __hip_atomic_load(p, __ATOMIC_RELAXED, __HIP_MEMORY_SCOPE_AGENT);
        if ((v & 3u) == want) break;
        if ((++g & 255) == 0) {
            if (__hip_atomic_load(abortf, __ATOMIC_RELAXED, __HIP_MEMORY_SCOPE_AGENT) != 0) break;
            if (g > (1 << 19)) {  // deadlock valve: fail loudly, don't hang
                __hip_atomic_store(abortf, 1, __ATOMIC_RELAXED, __HIP_MEMORY_SCOPE_AGENT);
                break;
            }
        }
    }
    __asm__ volatile("" ::: "memory");
    return v;
}

// tagged 8B poll for argmax: wait until tag (high 32b, signed) >= want (R0 form)
__device__ __forceinline__ unsigned long long spin_tag(unsigned long long* p, int want, int* abortf)
{
    int g = 0;
    unsigned long long r;
    for (;;) {
        r = __hip_atomic_load(p, __ATOMIC_RELAXED, __HIP_MEMORY_SCOPE_AGENT);
        if ((int)(r >> 32) >= want) break;
        if ((++g & 255) == 0) {
            if (__hip_atomic_load(abortf, __ATOMIC_RELAXED, __HIP_MEMORY_SCOPE_AGENT) != 0) break;
            if (g > (1 << 19)) {
                __hip_atomic_store(abortf, 1, __ATOMIC_RELAXED, __HIP_MEMORY_SCOPE_AGENT);
                break;
            }
        }
    }
    __asm__ volatile("" ::: "memory");
    return r;
}

// ---------------------------------------------------------------------------
// Phase 2: persistent recurrence — R0 structure verbatim (proven 2530 us),
// with ONE change: the second row-set's weights (w1, 139 KB/WG) live in LDS
// (staged once, conflict-free transposed layout) instead of streaming from L2
// every step.  GEMV traffic: 139 KB L2 || 139 KB LDS per step (parallel pipes)
// instead of 277 KB L2.  Accumulation order verbatim -> bit-identical.
// ---------------------------------------------------------------------------
__global__ __launch_bounds__(512, 2) void rnn_persist(
    const float* __restrict__ gi,
    const float* __restrict__ encWhh, const float* __restrict__ encBhh,
    const float* __restrict__ decWhh, const float* __restrict__ decBhh,
    const float* __restrict__ tab,
    const float* __restrict__ linW, const float* __restrict__ linB,
    const int* __restrict__ target,
    unsigned int* hpk, unsigned long long* amax, int* abortf, float* out)
{
    const int w = blockIdx.x;
    const int b = w & 63;
    const int s = w >> 6;
    const int tid = threadIdx.x;

    extern __shared__ float smem[];
    float* w2t     = smem + SM_W2T;
    float* hbuf    = smem + SM_HB;
    float* partU   = smem + SM_PART;    // [4][228] flat
    float* lpartU  = smem + SM_LPART;   // [32][9] flat
    float* logit_s = smem + SM_LOGS;
    float* amx_v   = smem + SM_AMXV;
    int*   amx_i   = (int*)(smem + SM_AMXI);

    const bool comp = (tid < 456);
    const int ksq = tid / 114;          // k-group 0..3 (k-window [76*ksq, 76*ksq+76))
    const int lp  = tid - ksq * 114;    // row-pair index 0..113; rows lp and lp+114
    const int g0 = lp / US,        ul0 = lp - g0 * US;
    const int Rrow0 = g0 * HN + s * US + ul0;
    const int u = s * US + tid;         // global hidden unit for tid<76
    const int cq = tid / US;            // slice owning element `tid` (tid<304)

    unsigned long long* amx = amax + b * 4;
    unsigned int* hpb = hpk + b * HN;   // parity stride = NB*HN

    // ---- stage second row-set weights into LDS (conflict-free transposed):
    // w2t float4 index (kq*19 + j)*114 + lp holds row Rrow1(lp), k-quarter kq,
    // floats [j*4 .. j*4+3].
    auto stage_w2 = [&](const float* __restrict__ W) {
        for (int i = tid; i < 34656; i += 512) {
            const int e   = i & 3;
            const int blk = i >> 2;
            const int lp_ = blk % 114;
            const int kj  = blk / 114;
            const int j_  = kj % 19;
            const int kq_ = kj / 19;
            const int l2  = lp_ + 114;
            const int g1_ = l2 / US;
            const int ul_ = l2 - g1_ * US;
            const int row = g1_ * HN + s * US + ul_;
            w2t[i] = W[(size_t)row * HN + kq_ * US + j_ * 4 + e];
        }
    };
    stage_w2(encWhh);

    for (int i = tid; i < HN; i += 512) hbuf[i] = 0.f;   // h0 = 0

    // ---- encoder Whh row-set 0: 1 row x 76 k per thread (76 f32, L2-streamed)
    float4 wreg0[19];
    if (comp) {
        const float4* wp0 = (const float4*)(encWhh + (size_t)Rrow0 * HN + (size_t)ksq * US);
#pragma unroll
        for (int j = 0; j < 19; ++j) wreg0[j] = wp0[j];
    }
    float b_r = 0.f, b_z = 0.f, b_n = 0.f;
    if (tid < US) { b_r = encBhh[u]; b_z = encBhh[HN + u]; b_n = encBhh[2 * HN + u]; }

    __syncthreads();

    const float* gib = gi + (size_t)b * TSTEPS * G3;

    // ================= encoder: 1024 steps =================
    for (int t = 0; t < TSTEPS; ++t) {
        const int T = t + 1;                  // tag of the h this step produces
        float gr = 0.f, gz = 0.f, gn = 0.f;
        if (tid < US) {                       // gi load, hidden behind GEMV
            const float* gp = gib + (size_t)t * G3;
            gr = gp[u]; gz = gp[HN + u]; gn = gp[2 * HN + u];
        }
        if (comp) {                           // GEMV: row0 from L2 stream, row1 from LDS
            const float4* hp = (const float4*)(hbuf + ksq * US);
            const float4* wb = (const float4*)w2t + (ksq * 19) * 114 + lp;
            float acc0 = 0.f, acc1 = 0.f;
#pragma unroll
            for (int j = 0; j < 19; ++j) {
                const float4 h4 = hp[j];
                const float4 w0 = wreg0[j];
                const float4 w1 = wb[j * 114];
                acc0 += w0.x * h4.x; acc0 += w0.y * h4.y; acc0 += w0.z * h4.z; acc0 += w0.w * h4.w;
                acc1 += w1.x * h4.x; acc1 += w1.y * h4.y; acc1 += w1.z * h4.z; acc1 += w1.w * h4.w;
            }
            partU[ksq * RS + lp] = acc0;
            partU[ksq * RS + lp + 114] = acc1;
        }
        __syncthreads();                      // barrier 1: part done, hbuf reads done
        if (tid < US) {
            const float ghr = partU[tid] + partU[RS + tid] + partU[2 * RS + tid] + partU[3 * RS + tid] + b_r;
            const float ghz = partU[US + tid] + partU[RS + US + tid] + partU[2 * RS + US + tid] + partU[3 * RS + US + tid] + b_z;
            const float ghn = partU[2 * US + tid] + partU[RS + 2 * US + tid] + partU[2 * RS + 2 * US + tid] + partU[3 * RS + 2 * US + tid] + b_n;
            const float r = 1.f / (1.f + expf(-(gr + ghr)));
            const float z = 1.f / (1.f + expf(-(gz + ghz)));
            const float n = tanhf(gn + r * ghn);
            const float hnew = (1.f - z) * n + z * hbuf[u];
            const unsigned hb = (__float_as_uint(hnew) & ~3u) | ((unsigned)T & 3u);
            hbuf[u] = __uint_as_float(hb);    // own slice, tagged (bit-identical everywhere)
            __hip_atomic_store(&hpb[(T & 1) * NB * HN + u], hb,
                               __ATOMIC_RELAXED, __HIP_MEMORY_SCOPE_AGENT);
        }
        if (tid < HN && cq != s) {            // fetch remote slices: data IS the flag
            const unsigned v = poll_tag32(&hpb[(T & 1) * NB * HN + tid],
                                          (unsigned)T & 3u, abortf);
            hbuf[tid] = __uint_as_float(v);
        }
        __syncthreads();                      // barrier 2: hbuf = h_{t+1}
    }

    // ---- decoder weights + biases (row0 regs + row1 LDS re-stage)
    stage_w2(decWhh);
    if (comp) {
        const float4* wp0 = (const float4*)(decWhh + (size_t)Rrow0 * HN + (size_t)ksq * US);
#pragma unroll
        for (int j = 0; j < 19; ++j) wreg0[j] = wp0[j];
    }
    if (tid < US) { b_r = decBhh[u]; b_z = decBhh[HN + u]; b_n = decBhh[2 * HN + u]; }
    int tok = target[b * 128];         // target[b,0,0]
    const int lrow = tid >> 3;         // logit row within slice (tid<256)
    const int lks = tid & 7;           // 8 k-slices of 38
    __syncthreads();

    // ================= decoder: 127 steps =================
    for (int t = 0; t < LDEC; ++t) {
        const int T = TSTEPS + 1 + t;         // h tag this step produces
        float gr = 0.f, gz = 0.f, gn = 0.f;
        if (tid < US) {
            const float* tp = tab + (size_t)tok * G3;
            gr = tp[u]; gz = tp[HN + u]; gn = tp[2 * HN + u];
        }
        if (comp) {
            const float4* hp = (const float4*)(hbuf + ksq * US);
            const float4* wb = (const float4*)w2t + (ksq * 19) * 114 + lp;
            float acc0 = 0.f, acc1 = 0.f;
#pragma unroll
            for (int j = 0; j < 19; ++j) {
                const float4 h4 = hp[j];
                const float4 w0 = wreg0[j];
                const float4 w1 = wb[j * 114];
                acc0 += w0.x * h4.x; acc0 += w0.y * h4.y; acc0 += w0.z * h4.z; acc0 += w0.w * h4.w;
                acc1 += w1.x * h4.x; acc1 += w1.y * h4.y; acc1 += w1.z * h4.z; acc1 += w1.w * h4.w;
            }
            partU[ksq * RS + lp] = acc0;
            partU[ksq * RS + lp + 114] = acc1;
        }
        __syncthreads();
        if (tid < US) {
            const float ghr = partU[tid] + partU[RS + tid] + partU[2 * RS + tid] + partU[3 * RS + tid] + b_r;
            const float ghz = partU[US + tid] + partU[RS + US + tid] + partU[2 * RS + US + tid] + partU[3 * RS + US + tid] + b_z;
            const float ghn = partU[2 * US + tid] + partU[RS + 2 * US + tid] + partU[2 * RS + 2 * US + tid] + partU[3 * RS + 2 * US + tid] + b_n;
            const float r = 1.f / (1.f + expf(-(gr + ghr)));
            const float z = 1.f / (1.f + expf(-(gz + ghz)));
            const float n = tanhf(gn + r * ghn);
            const float hnew = (1.f - z) * n + z * hbuf[u];
            const unsigned hb = (__float_as_uint(hnew) & ~3u) | ((unsigned)T & 3u);
            hbuf[u] = __uint_as_float(hb);
            __hip_atomic_store(&hpb[(T & 1) * NB * HN + u], hb,
                               __ATOMIC_RELAXED, __HIP_MEMORY_SCOPE_AGENT);
        }
        if (tid < HN && cq != s) {
            const unsigned v = poll_tag32(&hpb[(T & 1) * NB * HN + tid],
                                          (unsigned)T & 3u, abortf);
            hbuf[tid] = __uint_as_float(v);
        }
        __syncthreads();                      // hbuf = fresh h for logits

        // logits rows [32s, 32s+32)  (R0-verbatim: global linW float2 loads)
        if (tid < 256) {
            const float2* wl = (const float2*)(linW + (size_t)(s * 32 + lrow) * HN + (size_t)lks * 38);
            const float2* hl = (const float2*)(hbuf + lks * 38);
            float a = 0.f;
#pragma unroll
            for (int j = 0; j < 19; ++j) { const float2 wv = wl[j], hv = hl[j]; a += wv.x * hv.x; a += wv.y * hv.y; }
            lpartU[lrow * 9 + lks] = a;
        }
        __syncthreads();
        if (tid < 32) {
            const float lg = lpartU[tid * 9 + 0] + lpartU[tid * 9 + 1] + lpartU[tid * 9 + 2] + lpartU[tid * 9 + 3]
                           + lpartU[tid * 9 + 4] + lpartU[tid * 9 + 5] + lpartU[tid * 9 + 6] + lpartU[tid * 9 + 7]
                           + linB[s * 32 + tid];
            logit_s[tid] = lg;
            out[((size_t)b * LDEC + t) * DCLS + s * 32 + tid] = lg;   // softmax_cal
        }
        __syncthreads();
        if (tid == 0) {                       // publish local argmax: one tagged 8B store
            float bv = logit_s[0]; int bi = 0;
            for (int i = 1; i < 32; ++i) { const float v = logit_s[i]; if (v > bv) { bv = v; bi = i; } }
            const unsigned tagf = (unsigned)(((t + 1) << 8) | (s * 32 + bi));
            const unsigned long long pk = ((unsigned long long)tagf << 32) | (unsigned long long)__float_as_uint(bv);
            __hip_atomic_store(&amx[s], pk, __ATOMIC_RELAXED, __HIP_MEMORY_SCOPE_AGENT);
        }
        if (tid < 4) {                        // poll all 4 slices' argmaxes in parallel
            const unsigned long long r = spin_tag(&amx[tid], (t + 1) << 8, abortf);
            amx_v[tid] = __uint_as_float((unsigned)r);
            amx_i[tid] = (int)(r >> 32) & 255;
        }
        __syncthreads();
        {                                     // identical winner on all threads
            float gbv = amx_v[0]; int gbi = amx_i[0];
            if (amx_v[1] > gbv) { gbv = amx_v[1]; gbi = amx_i[1]; }
            if (amx_v[2] > gbv) { gbv = amx_v[2]; gbi = amx_i[2]; }
            if (amx_v[3] > gbv) { gbv = amx_v[3]; gbi = amx_i[3]; }
            tok = gbi;
            if (tid == 0 && s == 0) out[OUT_O2 + (size_t)b * LDEC + t] = (float)gbi;  // asr_outputs
        }
    }
}

// ---------------------------------------------------------------------------
extern "C" void kernel_launch(void* const* d_in, const int* in_sizes, int n_in,
                              void* d_out, int out_size, void* d_ws, size_t ws_size,
                              hipStream_t stream)
{
    (void)in_sizes; (void)n_in; (void)out_size;
    const float* x      = (const float*)d_in[0];
    const int*   target = (const int*)  d_in[1];
    const float* emb    = (const float*)d_in[2];
    const float* encWih = (const float*)d_in[3];
    const float* encWhh = (const float*)d_in[4];
    const float* encBih = (const float*)d_in[5];
    const float* encBhh = (const float*)d_in[6];
    const float* decWih = (const float*)d_in[7];
    const float* decWhh = (const float*)d_in[8];
    const float* decBih = (const float*)d_in[9];
    const float* decBhh = (const float*)d_in[10];
    const float* linW   = (const float*)d_in[11];
    const float* linB   = (const float*)d_in[12];
    float* out = (float*)d_out;
    char* ws = (char*)d_ws;

    if (ws_size < WS_NEED) return;  // insufficient scratch: fail visibly

    float*              gi   = (float*)(ws + OFF_GI);
    unsigned int*       hpk  = (unsigned int*)(ws + OFF_HP);
    unsigned long long* amax = (unsigned long long*)(ws + OFF_AM);
    int*                abrt = (int*)(ws + OFF_ABRT);
    float*              tab  = (float*)(ws + OFF_TAB);

    // opt-in to >64KB dynamic LDS for rnn_persist (one-time, capture-safe)
    static bool s_attr_done = false;
    if (!s_attr_done) {
        (void)hipFuncSetAttribute(reinterpret_cast<const void*>(rnn_persist),
                                  hipFuncAttributeMaxDynamicSharedMemorySize, SMEM_BYTES);
        s_attr_done = true;
    }

    // zero tagged-h ping-pong, argmax slots, abort flag
    (void)hipMemsetAsync(ws + OFF_HP, 0, OFF_TAB - OFF_HP, stream);
    gi_gemm<<<dim3(512, 8), 256, 0, stream>>>(x, encWih, encBih, gi);
    table_k<<<456, 256, 0, stream>>>(emb, decWih, decBih, tab);
    tcal_k<<<32, 256, 0, stream>>>(target, out);
    rnn_persist<<<256, 512, SMEM_BYTES, stream>>>(gi, encWhh, encBhh, decWhh, decBhh, tab,
                                                  linW, linB, target, hpk, amax, abrt, out);
}